// Round 3
// baseline (78.732 us; speedup 1.0000x reference)
//
#include <hip/hip_runtime.h>
#include <hip/hip_fp16.h>

// SoftNCutsLoss on MI355X — R16.
// batch: (4,1,32,32,32) f32, preds: (4,8,32,32,32) f32 -> out: (4,) f32
//
// R16 = R15 with 2x resident waves per CU, same total work.
// R15 post-mortem: riders landed (78.5us) but gains < issue model => main
// (~33us) is LATENCY-bound at 4 waves/SIMD (2 blocks/CU, 72.5KB LDS).
// Grid is only 512 blocks (2/CU), so occupancy must come from WIDER blocks:
//  - NT=1024 (16 waves), 4 threads/voxel, quarter tables (32/31/31/31
//    single-voxel entries; R14 lesson: unroll budget = entries x body size,
//    and this body is R13's proven single-voxel body).
//  - __launch_bounds__(1024,8) -> 64-VGPR cap -> 8 waves/SIMD, 2 blocks/CU
//    = 32 waves/CU. Loop live-set ~40 VGPR (q loads moved after the loop,
//    own-address recomputed from SGPR kernel args).
//  - LDS union: staging (sB 6.5KB + sPk 26KB, dead after accumulate) overlaps
//    epilogue transpose valsT (512 x 20 f32 = 40KB) -> 40960 B/block.
//  - Hierarchical epilogue: classes 2/3 write vals[16]; classes 0/1 add
//    partner slot + write back; 16x32-reader column sum (R15's proven shape).
// Total thread-entry interactions, DS ops/CU, exp2 count: identical to R15.
// Math identical to R13/R15 (pairwise symmetry + negative-lex pad S).

#define EPS_F 2.220446049250313e-16f

constexpr int TD = 4, TH = 8, TW = 8;      // tile dims (d,h,w)
constexpr int HDh = 7, HHh = 14, HWh = 14; // halo: x forward-only +3, y/z +-3
constexpr int SYB = 17;                    // halo h-stride
constexpr int SXB = HHh * SYB;             // 238, halo d-stride
constexpr int NB  = 6 * SXB + 13 * SYB + 13 + 1;  // 1663 voxel slots
constexpr int NT = 1024;                   // threads per block (16 waves)
constexpr int NBLK = 512;                  // 4 batches * 128 tiles
constexpr int NTASK = HDh * HHh * 4;       // 392 staging tasks (row x 4 chunks)

constexpr int SB_BYTES  = ((NB * 4 + 15) / 16) * 16;   // 6656
constexpr int LDS_BYTES = 512 * 20 * 4;                // 40960 (>= 6656+26608)

// exponent folding: aff = exp2(d2*K1 + c2*K2)
#define K1F (-0.014426950408889634f)       // -0.01 * log2(e)
#define K2F (-0.09016844005556021f)        // -log2(e)/16

struct Ent { int off; float lw; };
struct QTab { Ent e[32]; int n; };

// lex-positive half ball (125 entries) split 4-way round-robin -> 32/31/31/31
constexpr QTab make_qtab(int cls) {
    QTab t{}; t.n = 0; int idx = 0;
    for (int dxq = 0; dxq < 4; ++dxq)
        for (int dyi = 0; dyi < 7; ++dyi)
            for (int dzi = 0; dzi < 7; ++dzi) {
                int dy = dyi - 3, dz = dzi - 3;
                if (dxq == 0) {                  // lexicographic positivity
                    if (dy < 0) continue;
                    if (dy == 0 && dz <= 0) continue;
                }
                int c2 = dxq * dxq + dy * dy + dz * dz;
                if (c2 >= 16) continue;          // ball cutoff
                const int my = idx & 3; ++idx;
                if (my != cls) continue;
                t.e[t.n].off = dxq * SXB + dy * SYB + dz;
                t.e[t.n].lw  = (float)c2 * K2F;
                ++t.n;
            }
    return t;
}
constexpr QTab QT0 = make_qtab(0);
constexpr QTab QT1 = make_qtab(1);
constexpr QTab QT2 = make_qtab(2);
constexpr QTab QT3 = make_qtab(3);

// ---------- constexpr border-S table: S(class_d, class_h, class_w) ----------
constexpr float W16[16] = {
    1.0f,                    0.93941306281347578611f, 0.88249690258459546286f,
    0.82902911818040034301f, 0.77880078307140486825f, 0.73161562894664190813f,
    0.68728927879097219970f, 0.64565423513106973593f, 0.60653065971263342360f,
    0.56978282473092302544f, 0.53526142851899028012f, 0.50283157797094090696f,
    0.47236655274101470713f, 0.44374731008100323837f, 0.41686201967850837523f,
    0.39160740400665634335f };

struct STab { float s[343]; };
constexpr STab make_stab() {
    STab t{};
    for (int a = 0; a < 7; ++a)
        for (int b = 0; b < 7; ++b)
            for (int c = 0; c < 7; ++c) {
                const int pa = a < 3 ? a : (a == 3 ? 16 : a + 25);
                const int pb = b < 3 ? b : (b == 3 ? 16 : b + 25);
                const int pc = c < 3 ? c : (c == 3 ? 16 : c + 25);
                float s = 0.f;
                for (int dx = -3; dx <= 3; ++dx)
                    for (int dy = -3; dy <= 3; ++dy)
                        for (int dz = -3; dz <= 3; ++dz) {
                            const int c2 = dx * dx + dy * dy + dz * dz;
                            if (c2 >= 16) continue;
                            const bool neg = (dx < 0) ||
                                (dx == 0 && (dy < 0 || (dy == 0 && dz < 0)));
                            if (!neg) continue;
                            const bool in = (pa + dx) >= 0 && (pa + dx) < 32 &&
                                            (pb + dy) >= 0 && (pb + dy) < 32 &&
                                            (pc + dz) >= 0 && (pc + dz) < 32;
                            if (!in) s += W16[c2];
                        }
                t.s[(a * 7 + b) * 7 + c] = s;
            }
    return t;
}
__constant__ STab STAB = make_stab();

__device__ __forceinline__ int bcls(int p) {
    return p < 3 ? p : (p > 28 ? p - 25 : 3);
}

__device__ __forceinline__ unsigned pack2(float a, float b) {
    return (unsigned)__half_as_ushort(__float2half(a)) |
           ((unsigned)__half_as_ushort(__float2half(b)) << 16);
}

template <int CLS>
__device__ __forceinline__ void accum_q(const float* __restrict__ sB,
                                        const uint4* __restrict__ sPk,
                                        int vown, float b_own,
                                        float acc[9]) {
    constexpr QTab T = CLS == 0 ? QT0 : CLS == 1 ? QT1 : CLS == 2 ? QT2 : QT3;
    constexpr int N = T.n;
    constexpr int N4 = (N / 4) * 4;

#pragma unroll
    for (int i = 0; i < N4; i += 4) {
        float sb[4];
        uint4 pk[4];
#pragma unroll
        for (int j = 0; j < 4; ++j) {
            const int nv = vown + T.e[i + j].off;
            sb[j] = sB[nv];
            pk[j] = sPk[nv];
        }
#pragma unroll
        for (int j = 0; j < 4; ++j) {
            const float d = b_own - sb[j];
            const float aff =
                __builtin_amdgcn_exp2f(__builtin_fmaf(d * d, K1F, T.e[i + j].lw));
            acc[8] += aff;
            __half2 h[4];
            __builtin_memcpy(h, &pk[j], 16);
            acc[0] = __builtin_fmaf(aff, __half2float(__low2half(h[0])),  acc[0]);
            acc[1] = __builtin_fmaf(aff, __half2float(__high2half(h[0])), acc[1]);
            acc[2] = __builtin_fmaf(aff, __half2float(__low2half(h[1])),  acc[2]);
            acc[3] = __builtin_fmaf(aff, __half2float(__high2half(h[1])), acc[3]);
            acc[4] = __builtin_fmaf(aff, __half2float(__low2half(h[2])),  acc[4]);
            acc[5] = __builtin_fmaf(aff, __half2float(__high2half(h[2])), acc[5]);
            acc[6] = __builtin_fmaf(aff, __half2float(__low2half(h[3])),  acc[6]);
            acc[7] = __builtin_fmaf(aff, __half2float(__high2half(h[3])), acc[7]);
        }
    }
#pragma unroll
    for (int i = N4; i < N; ++i) {               // remainder (<=3)
        const int nv = vown + T.e[i].off;
        const float sb = sB[nv];
        const uint4 pk = sPk[nv];
        const float d = b_own - sb;
        const float aff =
            __builtin_amdgcn_exp2f(__builtin_fmaf(d * d, K1F, T.e[i].lw));
        acc[8] += aff;
        __half2 h[4];
        __builtin_memcpy(h, &pk, 16);
        acc[0] = __builtin_fmaf(aff, __half2float(__low2half(h[0])),  acc[0]);
        acc[1] = __builtin_fmaf(aff, __half2float(__high2half(h[0])), acc[1]);
        acc[2] = __builtin_fmaf(aff, __half2float(__low2half(h[1])),  acc[2]);
        acc[3] = __builtin_fmaf(aff, __half2float(__high2half(h[1])), acc[3]);
        acc[4] = __builtin_fmaf(aff, __half2float(__low2half(h[2])),  acc[4]);
        acc[5] = __builtin_fmaf(aff, __half2float(__high2half(h[2])), acc[5]);
        acc[6] = __builtin_fmaf(aff, __half2float(__low2half(h[3])),  acc[6]);
        acc[7] = __builtin_fmaf(aff, __half2float(__high2half(h[3])), acc[7]);
    }
}

__global__ __launch_bounds__(NT, 8)
void softncuts_main(const float* __restrict__ batch,
                    const float* __restrict__ preds,
                    float* __restrict__ partials) {
    // LDS union: [ sB | sPk ] (accumulate phase) overlaps valsT (epilogue).
    __shared__ __align__(16) unsigned char smem[LDS_BYTES];   // 40960 B
    float* const sB    = (float*)smem;                        // [NB]
    uint4* const sPk   = (uint4*)(smem + SB_BYTES);           // [NB]
    float* const valsT = (float*)smem;                        // [512*20]

    const int bid  = blockIdx.x;
    const int bb   = bid >> 7;          // batch index 0..3
    const int tile = bid & 127;
    const int tw = tile & 3;            // -> w0 = tw*8
    const int th = (tile >> 2) & 3;     // -> h0 = th*8
    const int td = tile >> 4;           // -> d0 = td*4
    const int d0 = td * TD, h0 = th * TH, w0 = tw * TW;

    const int tid  = threadIdx.x;

    const float* bbase = batch + (size_t)bb * 32768;
    const float* pbase = preds + (size_t)bb * 8 * 32768;

    // ---- stage forward-x halo, float4-vectorized along w (proven path) ----
    if (tid < NTASK) {
        const int t   = tid;
        const int c   = t & 3;
        const int row = t >> 2;
        const int hh  = row % HHh;
        const int hd  = row / HHh;
        const int gd  = d0 + hd;
        const int gh  = h0 + hh - 3;
        const int gw0 = w0 - 4 + c * 4;
        const int hwb = c * 4 - 1;
        const bool fast = (gd < 32) & ((unsigned)gh < 32u) & (gw0 >= 0) & (gw0 + 3 < 32);
        if (fast) {
            const int sidx = (gd * 32 + gh) * 32 + gw0;   // 16B-aligned
            float4 pv[9];
            pv[0] = *(const float4*)(bbase + sidx);
#pragma unroll
            for (int k = 0; k < 8; ++k)
                pv[k + 1] = *(const float4*)(pbase + sidx + k * 32768);
#pragma unroll
            for (int e = 0; e < 4; ++e) {
                const int hw = hwb + e;
                if (hw < 0 || hw >= HWh) continue;
                const int f = hd * SXB + hh * SYB + hw;
                sB[f] = ((const float*)&pv[0])[e];
                unsigned u[4];
#pragma unroll
                for (int k = 0; k < 4; ++k)
                    u[k] = pack2(((const float*)&pv[2 * k + 1])[e],
                                 ((const float*)&pv[2 * k + 2])[e]);
                sPk[f] = make_uint4(u[0], u[1], u[2], u[3]);
            }
        } else {
#pragma unroll
            for (int e = 0; e < 4; ++e) {
                const int hw = hwb + e;
                if (hw < 0 || hw >= HWh) continue;
                const int gw = gw0 + e;
                const bool in = (gd < 32) & ((unsigned)gh < 32u) & ((unsigned)gw < 32u);
                const int sidx = (gd * 32 + gh) * 32 + gw;
                const int f = hd * SXB + hh * SYB + hw;
                sB[f] = in ? bbase[sidx] : EPS_F;
                unsigned u[4];
#pragma unroll
                for (int k = 0; k < 4; ++k)
                    u[k] = pack2(in ? pbase[sidx + (2 * k) * 32768]     : 0.f,
                                 in ? pbase[sidx + (2 * k + 1) * 32768] : 0.f);
                sPk[f] = make_uint4(u[0], u[1], u[2], u[3]);
            }
        }
    }
    __syncthreads();

    // ---- thread -> (voxel, quarter-table class) ----
    const int cid  = tid >> 8;          // 0..3, wave-uniform (4 waves/class)
    const int vtid = tid & 255;
    const int lw = vtid & 7;            // 0..7
    const int lh = (vtid >> 3) & 7;     // 0..7
    const int ld = vtid >> 6;           // 0..3

    const int gdo = d0 + ld, gho = h0 + lh, gwo = w0 + lw;
    const int sidx_own = (gdo * 32 + gho) * 32 + gwo;
    const float b_own = bbase[sidx_own];

    const int vown = ld * SXB + (lh + 3) * SYB + (lw + 3);

    float acc[9];
#pragma unroll
    for (int i = 0; i < 9; ++i) acc[i] = 0.f;

    switch (cid) {
        case 0:  accum_q<0>(sB, sPk, vown, b_own, acc); break;
        case 1:  accum_q<1>(sB, sPk, vown, b_own, acc); break;
        case 2:  accum_q<2>(sB, sPk, vown, b_own, acc); break;
        default: accum_q<3>(sB, sPk, vown, b_own, acc); break;
    }

    // ---- own preds loaded AFTER the loop (keeps loop live-set < 64 VGPR) ----
    float q[8];
#pragma unroll
    for (int k = 0; k < 8; ++k) q[k] = pbase[sidx_own + k * 32768];

    // ---- self + pad terms exactly once per voxel (class 0 only) ----
    float selfpad = 0.f;
    if (cid == 0) {
        const float S = STAB.s[(bcls(gdo) * 7 + bcls(gho)) * 7 + bcls(gwo)];
        const float db = b_own - EPS_F;
        selfpad = 1.f + S * __expf(db * db * -0.01f);
    }

    float vals[16];
#pragma unroll
    for (int k = 0; k < 8; ++k) {
        vals[k]     = q[k] * (2.f * acc[k] + ((cid == 0) ? q[k] : 0.f));
        vals[8 + k] = q[k] * (acc[8] + selfpad) + acc[k];
    }

    // ---- hierarchical LDS reduction (valsT aliases the staging buffers) ----
    __syncthreads();                     // all sB/sPk reads complete
    if (tid >= 512) {                    // classes 2,3 -> slots 0..511
        float* vr = &valsT[(tid - 512) * 20];
        ((float4*)vr)[0] = make_float4(vals[0],  vals[1],  vals[2],  vals[3]);
        ((float4*)vr)[1] = make_float4(vals[4],  vals[5],  vals[6],  vals[7]);
        ((float4*)vr)[2] = make_float4(vals[8],  vals[9],  vals[10], vals[11]);
        ((float4*)vr)[3] = make_float4(vals[12], vals[13], vals[14], vals[15]);
    }
    __syncthreads();
    if (tid < 512) {                     // classes 0,1: add partner, write back
        float* vr = &valsT[tid * 20];
        float4 p0 = ((float4*)vr)[0], p1 = ((float4*)vr)[1];
        float4 p2 = ((float4*)vr)[2], p3 = ((float4*)vr)[3];
        ((float4*)vr)[0] = make_float4(vals[0]  + p0.x, vals[1]  + p0.y,
                                       vals[2]  + p0.z, vals[3]  + p0.w);
        ((float4*)vr)[1] = make_float4(vals[4]  + p1.x, vals[5]  + p1.y,
                                       vals[6]  + p1.z, vals[7]  + p1.w);
        ((float4*)vr)[2] = make_float4(vals[8]  + p2.x, vals[9]  + p2.y,
                                       vals[10] + p2.z, vals[11] + p2.w);
        ((float4*)vr)[3] = make_float4(vals[12] + p3.x, vals[13] + p3.y,
                                       vals[14] + p3.z, vals[15] + p3.w);
    }
    __syncthreads();
    if (tid < 512) {                     // 16 values x 32 readers column sum
        const int val = tid >> 5;        // 0..15
        const int r   = tid & 31;
        float s = 0.f;
#pragma unroll
        for (int k = 0; k < 16; ++k)
            s += valsT[(r + 32 * k) * 20 + val];
        for (int off = 16; off; off >>= 1) s += __shfl_down(s, off, 32);
        if (r == 0) partials[val * NBLK + bid] = s;
    }
}

__global__ __launch_bounds__(1024)
void softncuts_finalize(const float* __restrict__ partials,
                        float* __restrict__ out) {
    __shared__ float red[64];
    const int tid = threadIdx.x;          // 0..1023
    const int group = tid >> 4;           // 0..63 = bb*16 + slot
    const int j0 = tid & 15;
    const int slot = group & 15;
    const int bb = group >> 4;

    const float* p = partials + slot * NBLK + bb * 128;   // 128 tiles per batch
    float s = 0.f;
#pragma unroll
    for (int k = 0; k < 8; ++k) s += p[j0 + 16 * k];
    for (int off = 8; off; off >>= 1) s += __shfl_down(s, off, 16);
    if (j0 == 0) red[group] = s;
    __syncthreads();

    if (tid < 4) {
        float accv = 0.f;
#pragma unroll
        for (int k = 0; k < 8; ++k)
            accv += red[tid * 16 + k] / red[tid * 16 + 8 + k];
        out[tid] = 8.0f - accv;
    }
}

extern "C" void kernel_launch(void* const* d_in, const int* in_sizes, int n_in,
                              void* d_out, int out_size, void* d_ws, size_t ws_size,
                              hipStream_t stream) {
    const float* batch = (const float*)d_in[0];
    const float* preds = (const float*)d_in[1];
    float* out      = (float*)d_out;
    float* partials = (float*)d_ws;   // 16*NBLK floats = 32 KB

    softncuts_main<<<dim3(NBLK), dim3(NT), 0, stream>>>(batch, preds, partials);
    softncuts_finalize<<<dim3(1), dim3(1024), 0, stream>>>(partials, out);
}

// Round 4
// 77.677 us; speedup vs baseline: 1.0136x; 1.0136x over previous
//
#include <hip/hip_runtime.h>
#include <hip/hip_fp16.h>

// SoftNCutsLoss on MI355X — R17.
// batch: (4,1,32,32,32) f32, preds: (4,8,32,32,32) f32 -> out: (4,) f32
//
// R17 = R15 with the accumulate loop ROLLED over a __constant__ table.
// R16 post-mortem: doubling resident waves (16->32/CU, same work) was exactly
// neutral => main's ~30us has a large occupancy-insensitive component. Issue
// model (LDS 7.4us/CU, VALU ~9us chip) leaves ~20us unexplained — matching the
// "fixed ~20us" R6/R9 fit. Theory: 2 paths x 62 entries x ~23 insts ~ 24KB of
// once-through unrolled code, streamed COLD every iteration (the 256MB ws fill
// cycles all of L2), serializes at the I-fetch front for every wave.
// Fix: one rolled loop (unroll_count(2), ~2KB) over __constant__ CTAB[2][64]:
//  - tables padded to 64 entries with lw=-1e4 (exp2 -> 0, off=0 safe) -> no
//    remainder path, both halves share the same code;
//  - table base via readfirstlane(half) -> provably uniform -> s_load_dwordx2
//    (K$), NOT the R12/R14 function-local-constexpr scratch pathology;
//  - ds_read addresses now vown+off with off in SGPR (v_add per entry).
// Staging, epilogue (LDS-transpose), S-table, finalize: R15-proven, unchanged.
// Math identical to R13/R15 (pairwise symmetry + negative-lex pad S).

#define EPS_F 2.220446049250313e-16f

constexpr int TD = 4, TH = 8, TW = 8;      // tile dims (d,h,w)
constexpr int HDh = 7, HHh = 14, HWh = 14; // halo: x forward-only +3, y/z +-3
constexpr int SYB = 17;                    // halo h-stride
constexpr int SXB = HHh * SYB;             // 238, halo d-stride
constexpr int NB  = 6 * SXB + 13 * SYB + 13 + 1;  // 1663 voxel slots
constexpr int NT = 512;                    // threads per block (8 waves)
constexpr int NBLK = 512;                  // 4 batches * 128 tiles
constexpr int NTASK = HDh * HHh * 4;       // 392 staging tasks (row x 4 chunks)

// exponent folding: aff = exp2(d2*K1 + c2*K2)
#define K1F (-0.014426950408889634f)       // -0.01 * log2(e)
#define K2F (-0.09016844005556021f)        // -log2(e)/16

struct Ent { int off; float lw; };
struct Tab { Ent e[64]; int n; };

constexpr Tab make_tab(int half) {
    Tab t{};
    t.n = 0;
    for (int dxq = 0; dxq < 4; ++dxq)
        for (int dyi = 0; dyi < 7; ++dyi)
            for (int dzi = 0; dzi < 7; ++dzi) {
                int dy = dyi - 3, dz = dzi - 3;
                if (dxq == 0) {                  // lexicographic positivity
                    if (dy < 0) continue;
                    if (dy == 0 && dz <= 0) continue;
                }
                int c2 = dxq * dxq + dy * dy + dz * dz;
                if (c2 >= 16) continue;          // ball cutoff
                if (((dyi + dzi) & 1) != half) continue;
                t.e[t.n].off = dxq * SXB + dy * SYB + dz;
                t.e[t.n].lw  = (float)c2 * K2F;
                ++t.n;                           // 62 / 63
            }
    // pad to 64: off=0 (reads own voxel, valid), lw=-1e4 -> exp2 -> 0 exactly
    for (int i = t.n; i < 64; ++i) { t.e[i].off = 0; t.e[i].lw = -10000.0f; }
    t.n = 64;
    return t;
}

struct CTab2 { Ent e[2][64]; };
constexpr CTab2 make_ctab() {
    CTab2 c{};
    const Tab a = make_tab(0), b = make_tab(1);
    for (int i = 0; i < 64; ++i) { c.e[0][i] = a.e[i]; c.e[1][i] = b.e[i]; }
    return c;
}
__constant__ CTab2 CTAB = make_ctab();

// ---------- constexpr border-S table: S(class_d, class_h, class_w) ----------
constexpr float W16[16] = {
    1.0f,                    0.93941306281347578611f, 0.88249690258459546286f,
    0.82902911818040034301f, 0.77880078307140486825f, 0.73161562894664190813f,
    0.68728927879097219970f, 0.64565423513106973593f, 0.60653065971263342360f,
    0.56978282473092302544f, 0.53526142851899028012f, 0.50283157797094090696f,
    0.47236655274101470713f, 0.44374731008100323837f, 0.41686201967850837523f,
    0.39160740400665634335f };

struct STab { float s[343]; };
constexpr STab make_stab() {
    STab t{};
    for (int a = 0; a < 7; ++a)
        for (int b = 0; b < 7; ++b)
            for (int c = 0; c < 7; ++c) {
                const int pa = a < 3 ? a : (a == 3 ? 16 : a + 25);
                const int pb = b < 3 ? b : (b == 3 ? 16 : b + 25);
                const int pc = c < 3 ? c : (c == 3 ? 16 : c + 25);
                float s = 0.f;
                for (int dx = -3; dx <= 3; ++dx)
                    for (int dy = -3; dy <= 3; ++dy)
                        for (int dz = -3; dz <= 3; ++dz) {
                            const int c2 = dx * dx + dy * dy + dz * dz;
                            if (c2 >= 16) continue;
                            const bool neg = (dx < 0) ||
                                (dx == 0 && (dy < 0 || (dy == 0 && dz < 0)));
                            if (!neg) continue;
                            const bool in = (pa + dx) >= 0 && (pa + dx) < 32 &&
                                            (pb + dy) >= 0 && (pb + dy) < 32 &&
                                            (pc + dz) >= 0 && (pc + dz) < 32;
                            if (!in) s += W16[c2];
                        }
                t.s[(a * 7 + b) * 7 + c] = s;
            }
    return t;
}
__constant__ STab STAB = make_stab();

__device__ __forceinline__ int bcls(int p) {
    return p < 3 ? p : (p > 28 ? p - 25 : 3);
}

__device__ __forceinline__ unsigned pack2(float a, float b) {
    return (unsigned)__half_as_ushort(__float2half(a)) |
           ((unsigned)__half_as_ushort(__float2half(b)) << 16);
}

// Rolled accumulate loop: ~2KB of code shared by both halves. Table entries
// are wave-uniform scalar loads; DS addresses are vown + sgpr offset.
__device__ __forceinline__ void accum_rolled(const float* __restrict__ sB,
                                             const uint4* __restrict__ sPk,
                                             int vown, float b_own,
                                             const Ent* __restrict__ tab,
                                             float acc[9]) {
#pragma clang loop unroll_count(2)
    for (int i = 0; i < 64; i += 4) {
        float sb[4];
        uint4 pk[4];
        float lwv[4];
#pragma unroll
        for (int j = 0; j < 4; ++j) {
            const int off = tab[i + j].off;     // s_load_dwordx2 (uniform)
            lwv[j] = tab[i + j].lw;
            const int nv = vown + off;
            sb[j] = sB[nv];
            pk[j] = sPk[nv];
        }
#pragma unroll
        for (int j = 0; j < 4; ++j) {
            const float d = b_own - sb[j];
            const float aff =
                __builtin_amdgcn_exp2f(__builtin_fmaf(d * d, K1F, lwv[j]));
            acc[8] += aff;
            __half2 h[4];
            __builtin_memcpy(h, &pk[j], 16);
            acc[0] = __builtin_fmaf(aff, __half2float(__low2half(h[0])),  acc[0]);
            acc[1] = __builtin_fmaf(aff, __half2float(__high2half(h[0])), acc[1]);
            acc[2] = __builtin_fmaf(aff, __half2float(__low2half(h[1])),  acc[2]);
            acc[3] = __builtin_fmaf(aff, __half2float(__high2half(h[1])), acc[3]);
            acc[4] = __builtin_fmaf(aff, __half2float(__low2half(h[2])),  acc[4]);
            acc[5] = __builtin_fmaf(aff, __half2float(__high2half(h[2])), acc[5]);
            acc[6] = __builtin_fmaf(aff, __half2float(__low2half(h[3])),  acc[6]);
            acc[7] = __builtin_fmaf(aff, __half2float(__high2half(h[3])), acc[7]);
        }
    }
}

__global__ __launch_bounds__(NT, 4)
void softncuts_main(const float* __restrict__ batch,
                    const float* __restrict__ preds,
                    float* __restrict__ partials) {
    __shared__ float sB[NB];            // batch halo, f32 (6.5 KB)
    __shared__ uint4 sPk[NB];           // preds halo, 8 x f16 packed (26 KB)
    __shared__ float valsT[NT * 20];    // epilogue transpose, row stride 20 (40 KB)

    const int bid  = blockIdx.x;
    const int bb   = bid >> 7;          // batch index 0..3
    const int tile = bid & 127;
    const int tw = tile & 3;            // -> w0 = tw*8
    const int th = (tile >> 2) & 3;     // -> h0 = th*8
    const int td = tile >> 4;           // -> d0 = td*4
    const int d0 = td * TD, h0 = th * TH, w0 = tw * TW;

    const int tid  = threadIdx.x;
    const int half = tid >> 8;          // 0/1, wave-uniform (waves 0-3 vs 4-7)
    const int vtid = tid & 255;
    const int lw = vtid & 7;            // 0..7
    const int lh = (vtid >> 3) & 7;     // 0..7
    const int ld = vtid >> 6;           // 0..3

    const float* bbase = batch + (size_t)bb * 32768;
    const float* pbase = preds + (size_t)bb * 8 * 32768;

    // ---- stage forward-x halo, float4-vectorized along w ----
    if (tid < NTASK) {
        const int t   = tid;
        const int c   = t & 3;
        const int row = t >> 2;
        const int hh  = row % HHh;
        const int hd  = row / HHh;
        const int gd  = d0 + hd;
        const int gh  = h0 + hh - 3;
        const int gw0 = w0 - 4 + c * 4;
        const int hwb = c * 4 - 1;
        const bool fast = (gd < 32) & ((unsigned)gh < 32u) & (gw0 >= 0) & (gw0 + 3 < 32);
        if (fast) {
            const int sidx = (gd * 32 + gh) * 32 + gw0;   // 16B-aligned
            float4 pv[9];
            pv[0] = *(const float4*)(bbase + sidx);
#pragma unroll
            for (int k = 0; k < 8; ++k)
                pv[k + 1] = *(const float4*)(pbase + sidx + k * 32768);
#pragma unroll
            for (int e = 0; e < 4; ++e) {
                const int hw = hwb + e;
                if (hw < 0 || hw >= HWh) continue;
                const int f = hd * SXB + hh * SYB + hw;
                sB[f] = ((const float*)&pv[0])[e];
                unsigned u[4];
#pragma unroll
                for (int k = 0; k < 4; ++k)
                    u[k] = pack2(((const float*)&pv[2 * k + 1])[e],
                                 ((const float*)&pv[2 * k + 2])[e]);
                sPk[f] = make_uint4(u[0], u[1], u[2], u[3]);
            }
        } else {
#pragma unroll
            for (int e = 0; e < 4; ++e) {
                const int hw = hwb + e;
                if (hw < 0 || hw >= HWh) continue;
                const int gw = gw0 + e;
                const bool in = (gd < 32) & ((unsigned)gh < 32u) & ((unsigned)gw < 32u);
                const int sidx = (gd * 32 + gh) * 32 + gw;
                const int f = hd * SXB + hh * SYB + hw;
                sB[f] = in ? bbase[sidx] : EPS_F;
                unsigned u[4];
#pragma unroll
                for (int k = 0; k < 4; ++k)
                    u[k] = pack2(in ? pbase[sidx + (2 * k) * 32768]     : 0.f,
                                 in ? pbase[sidx + (2 * k + 1) * 32768] : 0.f);
                sPk[f] = make_uint4(u[0], u[1], u[2], u[3]);
            }
        }
    }
    __syncthreads();

    // ---- own voxel values from GLOBAL f32 (full precision for b_own and q) ----
    const int gdo = d0 + ld, gho = h0 + lh, gwo = w0 + lw;
    const int sidx_own = (gdo * 32 + gho) * 32 + gwo;
    const float b_own = bbase[sidx_own];
    float q[8];
#pragma unroll
    for (int k = 0; k < 8; ++k) q[k] = pbase[sidx_own + k * 32768];

    const int vown = ld * SXB + (lh + 3) * SYB + (lw + 3);

    float acc[9];
#pragma unroll
    for (int i = 0; i < 9; ++i) acc[i] = 0.f;

    // uniform table base -> scalar loads inside the rolled loop
    const int halfu = __builtin_amdgcn_readfirstlane(half);
    accum_rolled(sB, sPk, vown, b_own, CTAB.e[halfu], acc);

    // ---- self + pad terms (table lookup, half==0 threads only) ----
    float selfpad = 0.f;
    if (half == 0) {
        const float S = STAB.s[(bcls(gdo) * 7 + bcls(gho)) * 7 + bcls(gwo)];
        const float db = b_own - EPS_F;
        selfpad = 1.f + S * __expf(db * db * -0.01f);
    }

    // ---- per-lane contributions (voxel shared by 2 threads; self terms once) ----
    float vals[16];
#pragma unroll
    for (int k = 0; k < 8; ++k) {
        vals[k]     = q[k] * (2.f * acc[k] + ((half == 0) ? q[k] : 0.f));
        vals[8 + k] = q[k] * (acc[8] + selfpad) + acc[k];
    }

    // ---- LDS-transpose block reduction ----
    {
        float* vr = &valsT[tid * 20];                 // 80 B rows, 16B aligned
        ((float4*)vr)[0] = make_float4(vals[0],  vals[1],  vals[2],  vals[3]);
        ((float4*)vr)[1] = make_float4(vals[4],  vals[5],  vals[6],  vals[7]);
        ((float4*)vr)[2] = make_float4(vals[8],  vals[9],  vals[10], vals[11]);
        ((float4*)vr)[3] = make_float4(vals[12], vals[13], vals[14], vals[15]);
    }
    __syncthreads();
    {
        const int val = tid >> 5;                     // 0..15
        const int r   = tid & 31;                     // 32 readers per value
        float s = 0.f;
#pragma unroll
        for (int k = 0; k < 16; ++k)
            s += valsT[(r + 32 * k) * 20 + val];
        for (int off = 16; off; off >>= 1) s += __shfl_down(s, off, 32);
        if (r == 0) partials[val * NBLK + bid] = s;
    }
}

__global__ __launch_bounds__(1024)
void softncuts_finalize(const float* __restrict__ partials,
                        float* __restrict__ out) {
    __shared__ float red[64];
    const int tid = threadIdx.x;          // 0..1023
    const int group = tid >> 4;           // 0..63 = bb*16 + slot
    const int j0 = tid & 15;
    const int slot = group & 15;
    const int bb = group >> 4;

    const float* p = partials + slot * NBLK + bb * 128;   // 128 tiles per batch
    float s = 0.f;
#pragma unroll
    for (int k = 0; k < 8; ++k) s += p[j0 + 16 * k];
    for (int off = 8; off; off >>= 1) s += __shfl_down(s, off, 16);
    if (j0 == 0) red[group] = s;
    __syncthreads();

    if (tid < 4) {
        float accv = 0.f;
#pragma unroll
        for (int k = 0; k < 8; ++k)
            accv += red[tid * 16 + k] / red[tid * 16 + 8 + k];
        out[tid] = 8.0f - accv;
    }
}

extern "C" void kernel_launch(void* const* d_in, const int* in_sizes, int n_in,
                              void* d_out, int out_size, void* d_ws, size_t ws_size,
                              hipStream_t stream) {
    const float* batch = (const float*)d_in[0];
    const float* preds = (const float*)d_in[1];
    float* out      = (float*)d_out;
    float* partials = (float*)d_ws;   // 16*NBLK floats = 32 KB

    softncuts_main<<<dim3(NBLK), dim3(NT), 0, stream>>>(batch, preds, partials);
    softncuts_finalize<<<dim3(1), dim3(1024), 0, stream>>>(partials, out);
}